// Round 1
// 450.491 us; speedup vs baseline: 1.1132x; 1.1132x over previous
//
#include <hip/hip_runtime.h>

#define N_NODES  200000
#define N_CHILD  32
#define N_LAYERS 8
#define CHUNK    20000   // floats per window; 2 windows * 80000 B = 160000 B LDS (max 163840)
#define NCHUNK   10
#define NB       256     // 1 block per CU
#define NPB      782     // ceil(200000/256) nodes per block
#define BT       832     // 13 waves; 782/832 = 94% lanes active
#define NWAVE    (BT / 64)               // 13
#define SEG4     ((CHUNK / 4 + 63) / 64) // 79 wave-segments of 64 float4 per window

#define AS1 __attribute__((address_space(1)))
#define AS3 __attribute__((address_space(3)))

// v4: async double-buffered staging. 10 windows of 78.1 KB, ping-pong in LDS.
// Window c+1 is staged via global_load_lds (async DMA, no L1/VGPR round-trip)
// BEFORE probing window c; __syncthreads() (compiler emits vmcnt(0)+barrier)
// then lands after the probe phase, so staging latency hides under probe
// compute. Probes stay branchless (cndmask addr + cndmask value).
__device__ __forceinline__ void stage_chunk_async(const float4* __restrict__ src4,
                                                  float4* dst4, int wave, int lane)
{
    #pragma unroll
    for (int sg = 0; sg < (SEG4 + NWAVE - 1) / NWAVE; ++sg) {
        const int seg = wave + sg * NWAVE;
        const int e   = (seg << 6) + lane;          // float4 index within window
        if (seg < SEG4 && e < CHUNK / 4) {
            __builtin_amdgcn_global_load_lds(
                (const AS1 void*)(const void*)(src4 + e),
                (AS3 void*)(void*)(dst4 + e),
                16, 0, 0);
        }
    }
}

__global__ __launch_bounds__(BT) void layer_kernel(
    const float* __restrict__ vals_in,
    float*       __restrict__ vals_out,
    const int*   __restrict__ child_idx,   // [N_NODES][N_CHILD] this layer
    const int*   __restrict__ fun_ids,     // [N_NODES] this layer
    const float* __restrict__ wptr)
{
    __shared__ __align__(16) float lds[2][CHUNK];
    const int tid    = threadIdx.x;
    const int wave   = tid >> 6;
    const int lane   = tid & 63;
    const int node   = blockIdx.x * NPB + tid;
    const bool active = (tid < NPB) && (node < N_NODES);

    const float4* __restrict__ src4 = (const float4*)vals_in;

    // get window 0 in flight before anything else
    stage_chunk_async(src4, (float4*)lds[0], wave, lane);

    // child indices -> registers (8x int4, coalesced); overlaps with stage(0)
    int idx[N_CHILD];
    int fid = 3;
    if (active) {
        const int4* ci = (const int4*)(child_idx + (size_t)node * N_CHILD);
        #pragma unroll
        for (int j = 0; j < N_CHILD / 4; ++j) {
            int4 c = ci[j];
            idx[4*j+0] = c.x; idx[4*j+1] = c.y;
            idx[4*j+2] = c.z; idx[4*j+3] = c.w;
        }
        fid = fun_ids[node];
    } else {
        #pragma unroll
        for (int j = 0; j < N_CHILD; ++j) idx[j] = 0;
    }

    __syncthreads();   // vmcnt(0) drain: window 0 fully staged by all waves

    float s = 0.0f;
    #pragma unroll 1
    for (int c = 0; c < NCHUNK; ++c) {
        // issue next window's DMA first -- its latency hides under the probes
        if (c + 1 < NCHUNK)
            stage_chunk_async(src4 + (size_t)(c + 1) * (CHUNK / 4),
                              (float4*)lds[(c + 1) & 1], wave, lane);

        const float* __restrict__ buf = lds[c & 1];
        const unsigned cbase = (unsigned)(c * CHUNK);
        #pragma unroll
        for (int j = 0; j < N_CHILD; ++j) {
            unsigned off = (unsigned)idx[j] - cbase;
            bool in  = off < (unsigned)CHUNK;
            float v  = buf[in ? off : 0u];   // always in-bounds, no branch
            s += in ? v : 0.0f;              // cndmask, no branch
        }
        // probes of buf[c&1] done (lgkmcnt) + stage(c+1) complete (vmcnt) + barrier
        __syncthreads();
    }

    if (active) {
        float x = wptr[0] * s;
        float y;
        if (fid == 0)      y = tanhf(x);
        else if (fid == 1) y = 1.0f / (1.0f + __expf(-x));  // safe at +-inf
        else if (fid == 2) y = fmaxf(x, 0.0f);
        else               y = x;
        vals_out[node] = y;
    }
}

extern "C" void kernel_launch(void* const* d_in, const int* in_sizes, int n_in,
                              void* d_out, int out_size, void* d_ws, size_t ws_size,
                              hipStream_t stream) {
    const float* X         = (const float*)d_in[0];
    const float* w         = (const float*)d_in[1];
    const int*   child_idx = (const int*)d_in[2];
    const int*   fun_ids   = (const int*)d_in[3];
    float*       out       = (float*)d_out;
    float*       bufA      = (float*)d_ws;   // 800 KB ping buffer

    const float* cur = X;
    for (int l = 0; l < N_LAYERS; ++l) {
        // even layers -> bufA, odd layers -> d_out; layer 7 (last) -> d_out
        float* nxt = (l & 1) ? out : bufA;
        layer_kernel<<<NB, BT, 0, stream>>>(
            cur, nxt,
            child_idx + (size_t)l * N_NODES * N_CHILD,
            fun_ids   + (size_t)l * N_NODES,
            w);
        cur = nxt;
    }
}